// Round 3
// baseline (234.112 us; speedup 1.0000x reference)
//
#include <hip/hip_runtime.h>
#include <stdint.h>

// HolographicFMLayer: out[b, p(i,j), n] = sum_m X[b,i,m] * X[b,j,(n-m)&63],
// pairs i<j of 24 fields, dim 64, batch 2048, fp32 in/out.
//
// R3: R2's transposed-circulant MFMA core (validated, absmax 0.25) +
//  (a) 4 batches per block, double-buffered LDS staging with register
//      prefetch: batch t+1's global loads issue under batch t's compute;
//      one barrier per batch; grid 2048 -> 512 blocks.
//  (b) nontemporal (streaming) output stores: d_out is write-once and the
//      store pattern is 64B half-line segments -> avoid L2 write-allocate.
//
// Core math (validated R2): per i, D[n][j] = sum_k A[n][k]*B[k][j] with
//   A[n][k] = x_i[(n-k)&63] from reversed-doubled r_i via aligned
//             ds_read_b64 x3 + branchless 64-bit funnel (6 distinct windows
//             beta=16..96 cover all 8 (mt,ks) tiles),
//   B[k][j] = X[j][k], contiguous-k fragments, loop-invariant per batch.
// MFMA C-layout (row=4q+r, col=ln): lane holds 4 consecutive n at fixed j
// -> global_store_dwordx4; consecutive j -> consecutive pair rows.

typedef __bf16 bf16x8 __attribute__((ext_vector_type(8)));
typedef float  f32x4  __attribute__((ext_vector_type(4)));

#define NF        24
#define DIM       64
#define NPAIR     276
// r rows: 128 bf16 (256 B) + 8 B pad so ds_read_b64 at word dw+2 stays
// in-row; 264 keeps 8 B alignment.
#define RSTRIDE   264
#define XB_OFF    (NF * RSTRIDE)          // 6336 B
#define XB_STRIDE 72                       // elems; 144 B rows, 16B-aligned
#define BUF_BYTES (XB_OFF + 32 * XB_STRIDE * 2)   // 10944 B per buffer
#define BPB       4                        // batches per block

__global__ __launch_bounds__(256, 2)
void holo_fm_kernel(const float* __restrict__ in, float* __restrict__ out, int batches)
{
    __shared__ __align__(16) unsigned char lds[2 * BUF_BYTES];   // 21888 B

    const int tid  = threadIdx.x;
    const int lane = tid & 63;
    const int wave = tid >> 6;
    const int ln   = lane & 15;   // B col j in tile / output col
    const int q    = lane >> 4;   // k-quad (A/B) ; n-row-quad (C/D)
    const int b0   = blockIdx.x * BPB;

    // Zero B-pad rows 24..31 of BOTH buffers once; staging never writes them.
    #pragma unroll
    for (int buf = 0; buf < 2; ++buf) {
        __bf16* xb = (__bf16*)(lds + buf * BUF_BYTES + XB_OFF);
        for (int e = tid; e < (32 - NF) * XB_STRIDE; e += 256)
            xb[NF * XB_STRIDE + e] = (__bf16)0.0f;
    }

    auto loadRegs = [&](float* dst, int batch) {
        const float* xin = in + (size_t)batch * (NF * DIM);   // 1536 = 6*256
        #pragma unroll
        for (int r = 0; r < 6; ++r) dst[r] = xin[tid + 256 * r];
    };

    auto stage = [&](int buf, const float* vals) {
        unsigned char* base = lds + buf * BUF_BYTES;
        __bf16* xb = (__bf16*)(base + XB_OFF);
        #pragma unroll
        for (int r = 0; r < 6; ++r) {
            int e = tid + 256 * r;
            int f = e >> 6, m = e & 63;
            __bf16 v = (__bf16)vals[r];
            xb[f * XB_STRIDE + m] = v;           // xb[f][m] = bf16(X[f][m])
            __bf16* rr = (__bf16*)(base + f * RSTRIDE);
            int u0 = (64 - m) & 63;              // r_f[u] = X[f][(-u)&63]
            rr[u0]      = v;
            rr[u0 + 64] = v;                     // doubled for windowing
        }
    };

    auto compute = [&](int buf, int batch) {
        const unsigned char* base = lds + buf * BUF_BYTES;
        const __bf16* xb = (const __bf16*)(base + XB_OFF);

        // B fragments: B[k=32ks+8q+t][j=16jt+ln] = X[j][k]; batch-invariant.
        bf16x8 bfrag[2][2];
        #pragma unroll
        for (int jt = 0; jt < 2; ++jt)
            #pragma unroll
            for (int ks = 0; ks < 2; ++ks)
                bfrag[jt][ks] = *(const bf16x8*)(xb + (jt * 16 + ln) * XB_STRIDE + ks * 32 + q * 8);

        float* gbase = out + (size_t)batch * NPAIR * DIM;

        for (int i = wave; i < NF - 1; i += 4) {
            const uint64_t* ri = (const uint64_t*)(base + i * RSTRIDE);
            const int p0 = 23 * i - (i * (i - 1)) / 2;   // pidx of (i, i+1)

            // 6 circulant windows: awin[w] holds A[n][k]=r_i[16(w+1)+8q+t-ln].
            bf16x8 awin[6];
            #pragma unroll
            for (int w = 0; w < 6; ++w) {
                int ob = 2 * (16 * (w + 1) + 8 * q - ln);  // bytes, in [2,240]
                int dw = ob >> 3;
                int sh = (ob & 7) * 8;                      // 0/16/32/48
                uint64_t w0 = ri[dw], w1 = ri[dw + 1], w2 = ri[dw + 2];
                uint64_t lo = (w0 >> sh) | ((w1 << 1) << (63 - sh));
                uint64_t hi = (w1 >> sh) | ((w2 << 1) << (63 - sh));
                union { uint64_t u[2]; bf16x8 v; } cv;
                cv.u[0] = lo; cv.u[1] = hi;
                awin[w] = cv.v;
            }

            const int jtlo = (i < 15) ? 0 : 1;
            for (int jt = jtlo; jt < 2; ++jt) {
                const int j = 16 * jt + ln;
                const bool valid = (j > i) & (j < NF);
                float* orow = gbase + ((size_t)(p0 + j - i - 1)) * DIM + 4 * q;
                #pragma unroll
                for (int mt = 0; mt < 4; ++mt) {
                    f32x4 c = {0.f, 0.f, 0.f, 0.f};
                    c = __builtin_amdgcn_mfma_f32_16x16x32_bf16(awin[3 - mt], bfrag[jt][0], c, 0, 0, 0);
                    c = __builtin_amdgcn_mfma_f32_16x16x32_bf16(awin[5 - mt], bfrag[jt][1], c, 0, 0, 0);
                    if (valid)
                        __builtin_nontemporal_store(c, (f32x4*)(orow + 16 * mt));
                }
            }
        }
    };

    // Software pipeline: stage(0,batch0); loads for batch1 fly under compute0.
    float pa[6], pb[6];
    loadRegs(pa, b0);
    stage(0, pa);
    if (b0 + 1 < batches) loadRegs(pb, b0 + 1);
    __syncthreads();

    #pragma unroll
    for (int t = 0; t < BPB; ++t) {
        if (b0 + t < batches) compute(t & 1, b0 + t);
        if (t + 1 < BPB) {
            if (b0 + t + 1 < batches) stage((t + 1) & 1, (t & 1) ? pa : pb);
            if (t + 2 < BPB && b0 + t + 2 < batches) loadRegs((t & 1) ? pb : pa, b0 + t + 2);
            __syncthreads();
        }
    }
}

extern "C" void kernel_launch(void* const* d_in, const int* in_sizes, int n_in,
                              void* d_out, int out_size, void* d_ws, size_t ws_size,
                              hipStream_t stream)
{
    const float* in  = (const float*)d_in[0];
    float*       out = (float*)d_out;
    const int batches = in_sizes[0] / (NF * DIM);           // 2048
    const int blocks  = (batches + BPB - 1) / BPB;          // 512
    holo_fm_kernel<<<dim3(blocks), dim3(256), 0, stream>>>(in, out, batches);
}